// Round 16
// baseline (24.666 us; speedup 1.0000x reference)
//
#include <hip/hip_runtime.h>
#include <math.h>

#define NQ 4

typedef _Float16 f16;
typedef _Float16 f16x8 __attribute__((ext_vector_type(8)));
typedef __fp16 fp16x2 __attribute__((ext_vector_type(2)));   // cvt_pkrtz return type
typedef float f32x4 __attribute__((ext_vector_type(4)));
typedef float v2f __attribute__((ext_vector_type(2)));

#define K_TANH 2.885390081777927f     // 2*log2(e): tanh(x)=1-2/(2^(Kx)+1)
#define BETA2  0.15915494309189535f   // 1/(2*pi): full angle -> revolutions

__device__ __forceinline__ v2f b2(float s) { v2f r; r.x = s; r.y = s; return r; }

// packed pair tanh, inputs pre-scaled by K_TANH
__device__ __forceinline__ v2f tanh4v(v2f a) {
    v2f e;
    e.x = __builtin_amdgcn_exp2f(a.x);
    e.y = __builtin_amdgcn_exp2f(a.y);
    v2f d = e + 1.0f;
    v2f r;
    r.x = __builtin_amdgcn_rcpf(d.x);
    r.y = __builtin_amdgcn_rcpf(d.y);
    return __builtin_elementwise_fma(b2(-2.0f), r, b2(1.0f));
}
// packed pair tanh, unscaled inputs
__device__ __forceinline__ v2f tanh5v(v2f a) {
    return tanh4v(a * K_TANH);
}

union U8 { f16x8 v8; fp16x2 v2[4]; };

__shared__ float z2s[256][20];  // z2 transpose, wave-local rows; 16B-aligned rows
__shared__ float cpre[12];      // c[4], s[4] of layer-1 angles; u[4]=qw0*BETA2

extern "C" __global__ void __launch_bounds__(256, 6)
hybrid_pinn_kernel(const float* __restrict__ x,
                   const float* __restrict__ ew1, const float* __restrict__ eb1,
                   const float* __restrict__ ew2, const float* __restrict__ eb2,
                   const float* __restrict__ pw,  const float* __restrict__ pb,
                   const float* __restrict__ qw,
                   const float* __restrict__ pw1, const float* __restrict__ pb1,
                   const float* __restrict__ pw2, const float* __restrict__ pb2,
                   float* __restrict__ out)
{
    const int tid   = threadIdx.x;
    const int lane  = tid & 63;
    const int wbase = (tid >> 6) * 64;
    const int brow0 = blockIdx.x * 256;
    const int ak    = (lane >> 4) * 8;
    const int bn    = lane & 15;

    // ---- per-block: layer-1 trig + layer-0 revolution offsets ----
    if (tid < 4) {
        float s, c;
        __sincosf(qw[4 + tid], &s, &c);     // FULL layer-1 angle
        cpre[tid] = c; cpre[4 + tid] = s;
        cpre[8 + tid] = qw[tid] * BETA2;    // layer-0 offset in revolutions
    }
    __syncthreads();

    // ---- B-fragments of ew2 (64x16), K-scaled, f16 via pkrtz ----
    U8 bf0, bf1;
#pragma unroll
    for (int p = 0; p < 4; ++p) {
        v2f w0, w1;
        w0.x = ew2[(ak + 2 * p) * 16 + bn];
        w0.y = ew2[(ak + 2 * p + 1) * 16 + bn];
        w1.x = ew2[(32 + ak + 2 * p) * 16 + bn];
        w1.y = ew2[(32 + ak + 2 * p + 1) * 16 + bn];
        w0 = w0 * K_TANH;                  // v_pk_mul_f32
        w1 = w1 * K_TANH;
        bf0.v2[p] = __builtin_amdgcn_cvt_pkrtz(w0.x, w0.y);
        bf1.v2[p] = __builtin_amdgcn_cvt_pkrtz(w1.x, w1.y);
    }

    // ---- x rows this lane's A-fragments cover ----
    const float2* x2 = reinterpret_cast<const float2*>(x);
    float2 xr[4];
#pragma unroll
    for (int mt = 0; mt < 4; ++mt)
        xr[mt] = x2[brow0 + wbase + (lane & 15) + mt * 16];

    // ---- A-fragments: z1 = tanh(K*layer1); packed fma + packed tanh + pkrtz ----
    f16x8 afrag[4][2];
#pragma unroll
    for (int kt = 0; kt < 2; ++kt) {
        const int base = kt * 32 + ak;
        v2f w0[4], w1[4], bb[4];
#pragma unroll
        for (int p = 0; p < 4; ++p) {
            w0[p] = *reinterpret_cast<const v2f*>(&ew1[base + 2 * p]) * K_TANH;
            w1[p] = *reinterpret_cast<const v2f*>(&ew1[64 + base + 2 * p]) * K_TANH;
            bb[p] = *reinterpret_cast<const v2f*>(&eb1[base + 2 * p]) * K_TANH;
        }
#pragma unroll
        for (int mt = 0; mt < 4; ++mt) {
            U8 u;
#pragma unroll
            for (int p = 0; p < 4; ++p) {
                v2f a = __builtin_elementwise_fma(
                            b2(xr[mt].y), w1[p],
                            __builtin_elementwise_fma(b2(xr[mt].x), w0[p], bb[p]));
                v2f t = tanh4v(a);
                u.v2[p] = __builtin_amdgcn_cvt_pkrtz(t.x, t.y);
            }
            afrag[mt][kt] = u.v8;
        }
    }

    // ---- 8 MFMAs; K-scaled bias folded into C-init (per-column constant) ----
    const float ebc = eb2[bn] * K_TANH;
    f32x4 acc[4];
#pragma unroll
    for (int mt = 0; mt < 4; ++mt) {
        f32x4 z = {ebc, ebc, ebc, ebc};
        z = __builtin_amdgcn_mfma_f32_16x16x32_f16(afrag[mt][0], bf0.v8, z, 0, 0, 0);
        z = __builtin_amdgcn_mfma_f32_16x16x32_f16(afrag[mt][1], bf1.v8, z, 0, 0, 0);
        acc[mt] = z;
    }
    // C layout: col = lane&15, row = mt*16 + (lane>>4)*4 + j  (wave-local rows)
#pragma unroll
    for (int mt = 0; mt < 4; ++mt) {
#pragma unroll
        for (int j = 0; j < 4; ++j)
            z2s[wbase + mt * 16 + (lane >> 4) * 4 + j][bn] = acc[mt][j];
    }
    // no barrier: transpose is wave-local; lgkmcnt ordering suffices

    // ---- own row's z2 (K-scaled + biased), packed tanh ----
    float z2[16];
    {
        float4 r0 = *reinterpret_cast<const float4*>(&z2s[tid][0]);
        float4 r1 = *reinterpret_cast<const float4*>(&z2s[tid][4]);
        float4 r2 = *reinterpret_cast<const float4*>(&z2s[tid][8]);
        float4 r3 = *reinterpret_cast<const float4*>(&z2s[tid][12]);
        z2[0]=r0.x; z2[1]=r0.y; z2[2]=r0.z; z2[3]=r0.w;
        z2[4]=r1.x; z2[5]=r1.y; z2[6]=r1.z; z2[7]=r1.w;
        z2[8]=r2.x; z2[9]=r2.y; z2[10]=r2.z; z2[11]=r2.w;
        z2[12]=r3.x; z2[13]=r3.y; z2[14]=r3.z; z2[15]=r3.w;
    }
#pragma unroll
    for (int j = 0; j < 8; ++j) {
        v2f t; t.x = z2[2 * j]; t.y = z2[2 * j + 1];
        t = tanh4v(t);
        z2[2 * j] = t.x; z2[2 * j + 1] = t.y;
    }

    // ---- pre: 16 -> 4 (packed pairs) ----
    v2f tq01 = *reinterpret_cast<const v2f*>(&pb[0]);
    v2f tq23 = *reinterpret_cast<const v2f*>(&pb[2]);
#pragma unroll
    for (int i = 0; i < 16; ++i) {
        v2f zi = b2(z2[i]);
        tq01 = __builtin_elementwise_fma(zi, *reinterpret_cast<const v2f*>(&pw[i * 4]),     tq01);
        tq23 = __builtin_elementwise_fma(zi, *reinterpret_cast<const v2f*>(&pw[i * 4 + 2]), tq23);
    }

    // ---- per-row sincos of fused angles psi_j = qin_j + qw0_j ----
    float C0, C1, C2, C3, S0, S1, S2, S3;
    {
        float t0 = __builtin_amdgcn_fractf(fmaf(tq01.x, BETA2, cpre[8]));
        float t1 = __builtin_amdgcn_fractf(fmaf(tq01.y, BETA2, cpre[9]));
        float t2 = __builtin_amdgcn_fractf(fmaf(tq23.x, BETA2, cpre[10]));
        float t3 = __builtin_amdgcn_fractf(fmaf(tq23.y, BETA2, cpre[11]));
        S0 = __builtin_amdgcn_sinf(t0); C0 = __builtin_amdgcn_cosf(t0);
        S1 = __builtin_amdgcn_sinf(t1); C1 = __builtin_amdgcn_cosf(t1);
        S2 = __builtin_amdgcn_sinf(t2); C2 = __builtin_amdgcn_cosf(t2);
        S3 = __builtin_amdgcn_sinf(t3); C3 = __builtin_amdgcn_cosf(t3);
    }

    // ---- closed-form expectations (block-uniform coefficients) ----
    const float c0 = cpre[0], c1 = cpre[1], c2 = cpre[2], c3 = cpre[3];
    const float s0 = cpre[4], s1 = cpre[5], s2 = cpre[6], s3 = cpre[7];
    const float c12 = c1 * c2, s12 = s1 * s2, sc12 = s1 * c2, cs12 = c1 * s2;
    const float A1 = c12 * c3,  A2 = c12 * s3,  A3 = sc12 * c3, A4 = s12 * s3;
    const float B1 = c0 * c1,   B2 = s0 * s1;
    const float D1 = c0 * c12,  D2 = c0 * sc12, D3 = s0 * c12,  D4 = s0 * s12;
    const float c0s12 = c0 * s12, s0s12 = s0 * s12;
    const float E1 = D1 * c3,          E2 = (c0 * cs12) * c3;
    const float E3 = c0s12 * c3,       E4 = D3 * s3;
    const float E5 = (s0 * sc12) * c3, E6 = c0s12 * s3;
    const float E7 = (s0 * cs12) * s3, E8 = s0s12 * s3;

    // per-row monomials
    const float C01 = C0 * C1, C13 = C1 * C3, C02 = C0 * C2, C23 = C2 * C3;
    const float S01 = S0 * S1, S02 = S0 * S2, S12 = S1 * S2, S13 = S1 * S3;
    const float S23 = S2 * S3, C2S3 = C2 * S3;

    float qo[NQ];
    qo[0] = A1 * (C0 * C13) - A2 * (S01 * C2S3) - A3 * (S12 * C3) - A4 * S0;
    qo[1] = B1 * (C02 * C3) + B2 * S02;
    qo[2] = D1 * C13 - D2 * ((C0 * S12) * C3) - D3 * (S01 * C2) - D4 * (S0 * S3);
    qo[3] = E1 * C02 - E2 * (C1 * S23) + E3 * (C0 * S13) + E4 * C2S3
          + E5 * (S02 * C3) - E6 * ((S0 * C1) * C23) - E7 * (C01 * S2) + E8 * S1;

    // ---- post layer1: 4 -> 32, packed fma + packed tanh ----
    float h[32];
#pragma unroll
    for (int j = 0; j < 16; ++j) {
        v2f a = *reinterpret_cast<const v2f*>(&pb1[2 * j]);
#pragma unroll
        for (int i = 0; i < NQ; ++i)
            a = __builtin_elementwise_fma(b2(qo[i]),
                    *reinterpret_cast<const v2f*>(&pw1[i * 32 + 2 * j]), a);
        v2f t = tanh5v(a);
        h[2 * j]     = t.x;
        h[2 * j + 1] = t.y;
    }

    // ---- post layer2: 32 -> 4 (packed pairs) ----
    v2f o01 = *reinterpret_cast<const v2f*>(&pb2[0]);
    v2f o23 = *reinterpret_cast<const v2f*>(&pb2[2]);
#pragma unroll
    for (int i = 0; i < 32; ++i) {
        v2f hi = b2(h[i]);
        o01 = __builtin_elementwise_fma(hi, *reinterpret_cast<const v2f*>(&pw2[i * 4]),     o01);
        o23 = __builtin_elementwise_fma(hi, *reinterpret_cast<const v2f*>(&pw2[i * 4 + 2]), o23);
    }

    reinterpret_cast<float4*>(out)[brow0 + tid] = make_float4(o01.x, o01.y, o23.x, o23.y);
}

extern "C" void kernel_launch(void* const* d_in, const int* in_sizes, int n_in,
                              void* d_out, int out_size, void* d_ws, size_t ws_size,
                              hipStream_t stream) {
    const float* x   = (const float*)d_in[0];
    const float* ew1 = (const float*)d_in[1];
    const float* eb1 = (const float*)d_in[2];
    const float* ew2 = (const float*)d_in[3];
    const float* eb2 = (const float*)d_in[4];
    const float* pw  = (const float*)d_in[5];
    const float* pb  = (const float*)d_in[6];
    const float* qw  = (const float*)d_in[7];
    const float* pw1 = (const float*)d_in[8];
    const float* pb1 = (const float*)d_in[9];
    const float* pw2 = (const float*)d_in[10];
    const float* pb2 = (const float*)d_in[11];
    float* out = (float*)d_out;

    const int rows = in_sizes[0] / 2;   // 524288, multiple of 256
    hipLaunchKernelGGL(hybrid_pinn_kernel, dim3(rows / 256), dim3(256), 0, stream,
                       x, ew1, eb1, ew2, eb2, pw, pb, qw,
                       pw1, pb1, pw2, pb2, out);
}

// Round 17
// 23.762 us; speedup vs baseline: 1.0380x; 1.0380x over previous
//
#include <hip/hip_runtime.h>
#include <math.h>

#define NQ 4

typedef _Float16 f16;
typedef _Float16 f16x8 __attribute__((ext_vector_type(8)));
typedef __fp16 fp16x2 __attribute__((ext_vector_type(2)));   // cvt_pkrtz return type
typedef float f32x4 __attribute__((ext_vector_type(4)));
typedef float v2f __attribute__((ext_vector_type(2)));

#define K_TANH 2.885390081777927f     // 2*log2(e): tanh(x)=1-2/(2^(Kx)+1)
#define BETA2  0.15915494309189535f   // 1/(2*pi): full angle -> revolutions

__device__ __forceinline__ v2f b2(float s) { v2f r; r.x = s; r.y = s; return r; }

// packed pair tanh, inputs pre-scaled by K_TANH
__device__ __forceinline__ v2f tanh4v(v2f a) {
    v2f e;
    e.x = __builtin_amdgcn_exp2f(a.x);
    e.y = __builtin_amdgcn_exp2f(a.y);
    v2f d = e + 1.0f;
    v2f r;
    r.x = __builtin_amdgcn_rcpf(d.x);
    r.y = __builtin_amdgcn_rcpf(d.y);
    return __builtin_elementwise_fma(b2(-2.0f), r, b2(1.0f));
}
// packed pair tanh, unscaled inputs
__device__ __forceinline__ v2f tanh5v(v2f a) {
    return tanh4v(a * K_TANH);
}

union U8 { f16x8 v8; fp16x2 v2[4]; };

__shared__ float z2s[256][20];  // z2 transpose, wave-local rows; 16B-aligned rows
__shared__ float cpre[12];      // c[4], s[4] of layer-1 angles; u[4]=qw0*BETA2

extern "C" __global__ void __launch_bounds__(256)
hybrid_pinn_kernel(const float* __restrict__ x,
                   const float* __restrict__ ew1, const float* __restrict__ eb1,
                   const float* __restrict__ ew2, const float* __restrict__ eb2,
                   const float* __restrict__ pw,  const float* __restrict__ pb,
                   const float* __restrict__ qw,
                   const float* __restrict__ pw1, const float* __restrict__ pb1,
                   const float* __restrict__ pw2, const float* __restrict__ pb2,
                   float* __restrict__ out)
{
    const int tid   = threadIdx.x;
    const int lane  = tid & 63;
    const int wbase = (tid >> 6) * 64;
    const int brow0 = blockIdx.x * 256;
    const int ak    = (lane >> 4) * 8;
    const int bn    = lane & 15;

    // ---- per-block: layer-1 trig + layer-0 revolution offsets ----
    if (tid < 4) {
        float s, c;
        __sincosf(qw[4 + tid], &s, &c);     // FULL layer-1 angle
        cpre[tid] = c; cpre[4 + tid] = s;
        cpre[8 + tid] = qw[tid] * BETA2;    // layer-0 offset in revolutions
    }
    __syncthreads();

    // ---- B-fragments of ew2 (64x16), K-scaled, f16 via pkrtz ----
    U8 bf0, bf1;
#pragma unroll
    for (int p = 0; p < 4; ++p) {
        v2f w0, w1;
        w0.x = ew2[(ak + 2 * p) * 16 + bn];
        w0.y = ew2[(ak + 2 * p + 1) * 16 + bn];
        w1.x = ew2[(32 + ak + 2 * p) * 16 + bn];
        w1.y = ew2[(32 + ak + 2 * p + 1) * 16 + bn];
        w0 = w0 * K_TANH;                  // v_pk_mul_f32
        w1 = w1 * K_TANH;
        bf0.v2[p] = __builtin_amdgcn_cvt_pkrtz(w0.x, w0.y);
        bf1.v2[p] = __builtin_amdgcn_cvt_pkrtz(w1.x, w1.y);
    }

    // ---- x rows this lane's A-fragments cover ----
    const float2* x2 = reinterpret_cast<const float2*>(x);
    float2 xr[4];
#pragma unroll
    for (int mt = 0; mt < 4; ++mt)
        xr[mt] = x2[brow0 + wbase + (lane & 15) + mt * 16];

    // ---- A-fragments: z1 = tanh(K*layer1); packed fma + packed tanh + pkrtz ----
    f16x8 afrag[4][2];
#pragma unroll
    for (int kt = 0; kt < 2; ++kt) {
        const int base = kt * 32 + ak;
        v2f w0[4], w1[4], bb[4];
#pragma unroll
        for (int p = 0; p < 4; ++p) {
            w0[p] = *reinterpret_cast<const v2f*>(&ew1[base + 2 * p]) * K_TANH;
            w1[p] = *reinterpret_cast<const v2f*>(&ew1[64 + base + 2 * p]) * K_TANH;
            bb[p] = *reinterpret_cast<const v2f*>(&eb1[base + 2 * p]) * K_TANH;
        }
#pragma unroll
        for (int mt = 0; mt < 4; ++mt) {
            U8 u;
#pragma unroll
            for (int p = 0; p < 4; ++p) {
                v2f a = __builtin_elementwise_fma(
                            b2(xr[mt].y), w1[p],
                            __builtin_elementwise_fma(b2(xr[mt].x), w0[p], bb[p]));
                v2f t = tanh4v(a);
                u.v2[p] = __builtin_amdgcn_cvt_pkrtz(t.x, t.y);
            }
            afrag[mt][kt] = u.v8;
        }
    }

    // ---- 8 MFMAs; K-scaled bias folded into C-init (per-column constant) ----
    const float ebc = eb2[bn] * K_TANH;
    f32x4 acc[4];
#pragma unroll
    for (int mt = 0; mt < 4; ++mt) {
        f32x4 z = {ebc, ebc, ebc, ebc};
        z = __builtin_amdgcn_mfma_f32_16x16x32_f16(afrag[mt][0], bf0.v8, z, 0, 0, 0);
        z = __builtin_amdgcn_mfma_f32_16x16x32_f16(afrag[mt][1], bf1.v8, z, 0, 0, 0);
        acc[mt] = z;
    }
    // C layout: col = lane&15, row = mt*16 + (lane>>4)*4 + j  (wave-local rows)
#pragma unroll
    for (int mt = 0; mt < 4; ++mt) {
#pragma unroll
        for (int j = 0; j < 4; ++j)
            z2s[wbase + mt * 16 + (lane >> 4) * 4 + j][bn] = acc[mt][j];
    }
    // no barrier: transpose is wave-local; lgkmcnt ordering suffices

    // ---- own row's z2 (K-scaled + biased), packed tanh ----
    float z2[16];
    {
        float4 r0 = *reinterpret_cast<const float4*>(&z2s[tid][0]);
        float4 r1 = *reinterpret_cast<const float4*>(&z2s[tid][4]);
        float4 r2 = *reinterpret_cast<const float4*>(&z2s[tid][8]);
        float4 r3 = *reinterpret_cast<const float4*>(&z2s[tid][12]);
        z2[0]=r0.x; z2[1]=r0.y; z2[2]=r0.z; z2[3]=r0.w;
        z2[4]=r1.x; z2[5]=r1.y; z2[6]=r1.z; z2[7]=r1.w;
        z2[8]=r2.x; z2[9]=r2.y; z2[10]=r2.z; z2[11]=r2.w;
        z2[12]=r3.x; z2[13]=r3.y; z2[14]=r3.z; z2[15]=r3.w;
    }
#pragma unroll
    for (int j = 0; j < 8; ++j) {
        v2f t; t.x = z2[2 * j]; t.y = z2[2 * j + 1];
        t = tanh4v(t);
        z2[2 * j] = t.x; z2[2 * j + 1] = t.y;
    }

    // ---- pre: 16 -> 4 (packed pairs) ----
    v2f tq01 = *reinterpret_cast<const v2f*>(&pb[0]);
    v2f tq23 = *reinterpret_cast<const v2f*>(&pb[2]);
#pragma unroll
    for (int i = 0; i < 16; ++i) {
        v2f zi = b2(z2[i]);
        tq01 = __builtin_elementwise_fma(zi, *reinterpret_cast<const v2f*>(&pw[i * 4]),     tq01);
        tq23 = __builtin_elementwise_fma(zi, *reinterpret_cast<const v2f*>(&pw[i * 4 + 2]), tq23);
    }

    // ---- per-row sincos of fused angles psi_j = qin_j + qw0_j ----
    float C0, C1, C2, C3, S0, S1, S2, S3;
    {
        float t0 = __builtin_amdgcn_fractf(fmaf(tq01.x, BETA2, cpre[8]));
        float t1 = __builtin_amdgcn_fractf(fmaf(tq01.y, BETA2, cpre[9]));
        float t2 = __builtin_amdgcn_fractf(fmaf(tq23.x, BETA2, cpre[10]));
        float t3 = __builtin_amdgcn_fractf(fmaf(tq23.y, BETA2, cpre[11]));
        S0 = __builtin_amdgcn_sinf(t0); C0 = __builtin_amdgcn_cosf(t0);
        S1 = __builtin_amdgcn_sinf(t1); C1 = __builtin_amdgcn_cosf(t1);
        S2 = __builtin_amdgcn_sinf(t2); C2 = __builtin_amdgcn_cosf(t2);
        S3 = __builtin_amdgcn_sinf(t3); C3 = __builtin_amdgcn_cosf(t3);
    }

    // ---- closed-form expectations (block-uniform coefficients) ----
    const float c0 = cpre[0], c1 = cpre[1], c2 = cpre[2], c3 = cpre[3];
    const float s0 = cpre[4], s1 = cpre[5], s2 = cpre[6], s3 = cpre[7];
    const float c12 = c1 * c2, s12 = s1 * s2, sc12 = s1 * c2, cs12 = c1 * s2;
    const float A1 = c12 * c3,  A2 = c12 * s3,  A3 = sc12 * c3, A4 = s12 * s3;
    const float B1 = c0 * c1,   B2 = s0 * s1;
    const float D1 = c0 * c12,  D2 = c0 * sc12, D3 = s0 * c12,  D4 = s0 * s12;
    const float c0s12 = c0 * s12, s0s12 = s0 * s12;
    const float E1 = D1 * c3,          E2 = (c0 * cs12) * c3;
    const float E3 = c0s12 * c3,       E4 = D3 * s3;
    const float E5 = (s0 * sc12) * c3, E6 = c0s12 * s3;
    const float E7 = (s0 * cs12) * s3, E8 = s0s12 * s3;

    // per-row monomials
    const float C01 = C0 * C1, C13 = C1 * C3, C02 = C0 * C2, C23 = C2 * C3;
    const float S01 = S0 * S1, S02 = S0 * S2, S12 = S1 * S2, S13 = S1 * S3;
    const float S23 = S2 * S3, C2S3 = C2 * S3;

    float qo[NQ];
    qo[0] = A1 * (C0 * C13) - A2 * (S01 * C2S3) - A3 * (S12 * C3) - A4 * S0;
    qo[1] = B1 * (C02 * C3) + B2 * S02;
    qo[2] = D1 * C13 - D2 * ((C0 * S12) * C3) - D3 * (S01 * C2) - D4 * (S0 * S3);
    qo[3] = E1 * C02 - E2 * (C1 * S23) + E3 * (C0 * S13) + E4 * C2S3
          + E5 * (S02 * C3) - E6 * ((S0 * C1) * C23) - E7 * (C01 * S2) + E8 * S1;

    // ---- post layer1: 4 -> 32, packed fma + packed tanh ----
    float h[32];
#pragma unroll
    for (int j = 0; j < 16; ++j) {
        v2f a = *reinterpret_cast<const v2f*>(&pb1[2 * j]);
#pragma unroll
        for (int i = 0; i < NQ; ++i)
            a = __builtin_elementwise_fma(b2(qo[i]),
                    *reinterpret_cast<const v2f*>(&pw1[i * 32 + 2 * j]), a);
        v2f t = tanh5v(a);
        h[2 * j]     = t.x;
        h[2 * j + 1] = t.y;
    }

    // ---- post layer2: 32 -> 4 (packed pairs) ----
    v2f o01 = *reinterpret_cast<const v2f*>(&pb2[0]);
    v2f o23 = *reinterpret_cast<const v2f*>(&pb2[2]);
#pragma unroll
    for (int i = 0; i < 32; ++i) {
        v2f hi = b2(h[i]);
        o01 = __builtin_elementwise_fma(hi, *reinterpret_cast<const v2f*>(&pw2[i * 4]),     o01);
        o23 = __builtin_elementwise_fma(hi, *reinterpret_cast<const v2f*>(&pw2[i * 4 + 2]), o23);
    }

    reinterpret_cast<float4*>(out)[brow0 + tid] = make_float4(o01.x, o01.y, o23.x, o23.y);
}

extern "C" void kernel_launch(void* const* d_in, const int* in_sizes, int n_in,
                              void* d_out, int out_size, void* d_ws, size_t ws_size,
                              hipStream_t stream) {
    const float* x   = (const float*)d_in[0];
    const float* ew1 = (const float*)d_in[1];
    const float* eb1 = (const float*)d_in[2];
    const float* ew2 = (const float*)d_in[3];
    const float* eb2 = (const float*)d_in[4];
    const float* pw  = (const float*)d_in[5];
    const float* pb  = (const float*)d_in[6];
    const float* qw  = (const float*)d_in[7];
    const float* pw1 = (const float*)d_in[8];
    const float* pb1 = (const float*)d_in[9];
    const float* pw2 = (const float*)d_in[10];
    const float* pb2 = (const float*)d_in[11];
    float* out = (float*)d_out;

    const int rows = in_sizes[0] / 2;   // 524288, multiple of 256
    hipLaunchKernelGGL(hybrid_pinn_kernel, dim3(rows / 256), dim3(256), 0, stream,
                       x, ew1, eb1, ew2, eb2, pw, pb, qw,
                       pw1, pb1, pw2, pb2, out);
}